// Round 1
// 64.340 us; speedup vs baseline: 1.0115x; 1.0115x over previous
//
#include <hip/hip_runtime.h>

// Problem constants (from reference setup_inputs)
#define BATCH   32
#define CHANS   3
#define HW      4096      // 64*64, contiguous per (b,c) in NCHW fp32
#define NLEV    7
#define NEMBD   896
#define INNER   128       // 896 / 7
#define ROOTOFF 768       // (NLEV-1)*INNER
#define NCLS    1000
#define NRED    (BATCH * CHANS)   // 96 reduce slices == 96 blocks
#define NHEAD   63                // ceil(1000 / 16) head blocks

// Exact collapse of the reference:
//   g[b,c]     = mean_{h,w} x[b,c,h,w]        (every tree level's hw-mean == g)
//   wfold[c,j] = sum_l emb_w[(l*3+c)*896 + 768+j]
//   ebias[j]   = emb_b[768+j]
//   out[b,k]   = d[k] + sum_c g[b,c]*M[c,k]
//     M[c,k]   = sum_j wfold[c,j]*cls_w[j*1000+k]   (batch-independent!)
//     d[k]     = cls_b[k] + sum_j ebias[j]*cls_w[j*1000+k]
//
// V6: single fused kernel (was 2 dependent launches). All 96 blocks reduce
// one x-slice and publish g via agent-scope atomics; blocks 0..62 overlap
// the x-independent head phase (emb fold + cls_w read + M/d LDS reduce)
// with the other blocks' reductions, then spin on a monotonic epoch
// counter (no init needed: each launch adds exactly 96; snapshot-floor
// gives the epoch target; wrap/replay-safe). 96 blocks << 256 CUs and
// producers never spin -> no deadlock regardless of dispatch order.

__device__ unsigned g_done = 0;        // monotonic across launches
__device__ float    g_mean[NRED];      // written-before-read every launch

__global__ __launch_bounds__(256) void k_fused(
        const float* __restrict__ x,
        const float* __restrict__ emb_w,
        const float* __restrict__ emb_b,
        const float* __restrict__ cls_w,
        const float* __restrict__ cls_b,
        float* __restrict__ out) {
    const int t  = threadIdx.x;
    const int bc = blockIdx.x;                    // 0..95

    // Epoch target: snapshot BEFORE our own increment. Value is in
    // [L*96, L*96+95] (stream order guarantees prior launch drained),
    // so floor-to-96 recovers L exactly.
    unsigned target = 0;
    if (t == 0) {
        unsigned snap = __hip_atomic_load(&g_done, __ATOMIC_RELAXED,
                                          __HIP_MEMORY_SCOPE_AGENT);
        target = (snap / NRED) * NRED + NRED;
    }

    __shared__ float ls[4];

    // ---- Phase A (all 96 blocks): mean of own x slice, publish ASAP ----
    {
        const float4* p4 = (const float4*)(x + (size_t)bc * HW);
        float s = 0.f;
#pragma unroll
        for (int i = 0; i < 4; ++i) {
            float4 v = p4[t + 256 * i];
            s += (v.x + v.y) + (v.z + v.w);
        }
#pragma unroll
        for (int off = 32; off > 0; off >>= 1)
            s += __shfl_down(s, off, 64);
        if ((t & 63) == 0) ls[t >> 6] = s;
        __syncthreads();
        if (t == 0) {
            float mean = (ls[0] + ls[1] + ls[2] + ls[3]) * (1.0f / HW);
            __hip_atomic_store(&g_mean[bc], mean, __ATOMIC_RELAXED,
                               __HIP_MEMORY_SCOPE_AGENT);
            __hip_atomic_fetch_add(&g_done, 1u, __ATOMIC_RELEASE,
                                   __HIP_MEMORY_SCOPE_AGENT);
        }
    }

    if (bc >= NHEAD) return;   // blocks 63..95 are reduce-only

    // ---- Phase B (blocks 0..62): head. Everything up to the fan-out is
    // x-independent and overlaps other blocks' Phase A. ----
    const int tx = t & 15;
    const int ty = t >> 4;
    const int k  = bc * 16 + tx;
    const bool kok = (k < NCLS);

    __shared__ float wf0[INNER], wf1[INNER], wf2[INNER], eb[INNER];
    __shared__ float gsh[NRED];
    __shared__ float4 red[16][16];     // [ty][tx] partial (m0,m1,m2,d)
    __shared__ float4 fin[16];         // [tx] reduced

    if (t < INNER) {
        float a0 = 0.f, a1 = 0.f, a2 = 0.f;
#pragma unroll
        for (int l = 0; l < NLEV; ++l) {
            const float* row = emb_w + (size_t)(l * CHANS) * NEMBD + ROOTOFF + t;
            a0 += row[0 * NEMBD];
            a1 += row[1 * NEMBD];
            a2 += row[2 * NEMBD];
        }
        wf0[t] = a0; wf1[t] = a1; wf2[t] = a2;
        eb[t]  = emb_b[ROOTOFF + t];
    }
    __syncthreads();

    // partial M/d over this thread's 8 j's (cls_w loads all in flight)
    float m0 = 0.f, m1 = 0.f, m2 = 0.f, dd = 0.f;
    if (kok) {
        const int jb = ty * 8;
        float w[8];
#pragma unroll
        for (int jj = 0; jj < 8; ++jj)
            w[jj] = cls_w[(size_t)(jb + jj) * NCLS + k];
#pragma unroll
        for (int jj = 0; jj < 8; ++jj) {
            const int j = jb + jj;
            m0 += wf0[j] * w[jj];
            m1 += wf1[j] * w[jj];
            m2 += wf2[j] * w[jj];
            dd += eb[j]  * w[jj];
        }
    }
    red[ty][tx] = make_float4(m0, m1, m2, dd);
    __syncthreads();

    if (ty == 0) {
        float4 a = make_float4(0.f, 0.f, 0.f, kok ? cls_b[k] : 0.f);
#pragma unroll
        for (int yy = 0; yy < 16; ++yy) {
            float4 p = red[yy][tx];
            a.x += p.x; a.y += p.y; a.z += p.z; a.w += p.w;
        }
        fin[tx] = a;
    }

    // ---- Wait for all 96 means (thread 0 only), then fan out ----
    if (t == 0) {
        while ((int)(__hip_atomic_load(&g_done, __ATOMIC_ACQUIRE,
                                       __HIP_MEMORY_SCOPE_AGENT) - target) < 0)
            __builtin_amdgcn_s_sleep(1);
    }
    __syncthreads();   // orders spin + fin[] writes before readers

    if (t < NRED)
        gsh[t] = __hip_atomic_load(&g_mean[t], __ATOMIC_RELAXED,
                                   __HIP_MEMORY_SCOPE_AGENT);
    __syncthreads();

    if (kok) {
        const float4 m = fin[tx];
#pragma unroll
        for (int h = 0; h < 2; ++h) {
            const int b = ty + 16 * h;
            const float* gb = gsh + b * CHANS;
            out[(size_t)b * NCLS + k] = m.w + gb[0] * m.x + gb[1] * m.y + gb[2] * m.z;
        }
    }
}

extern "C" void kernel_launch(void* const* d_in, const int* in_sizes, int n_in,
                              void* d_out, int out_size, void* d_ws, size_t ws_size,
                              hipStream_t stream) {
    const float* x     = (const float*)d_in[0];
    const float* emb_w = (const float*)d_in[1];
    const float* emb_b = (const float*)d_in[2];
    const float* cls_w = (const float*)d_in[3];
    const float* cls_b = (const float*)d_in[4];
    float* out = (float*)d_out;
    (void)d_ws; (void)ws_size;   // workspace unused (g lives in __device__ mem)

    k_fused<<<NRED, 256, 0, stream>>>(x, emb_w, emb_b, cls_w, cls_b, out);
}

// Round 2
// 64.159 us; speedup vs baseline: 1.0144x; 1.0028x over previous
//
#include <hip/hip_runtime.h>

// Problem constants (from reference setup_inputs)
#define BATCH   32
#define CHANS   3
#define HW      4096      // 64*64, contiguous per (b,c) in NCHW fp32
#define NLEV    7
#define NEMBD   896
#define INNER   128       // 896 / 7
#define ROOTOFF 768       // (NLEV-1)*INNER
#define NCLS    1000
#define NRED    (BATCH * CHANS)   // 96 reduce slices == 96 blocks
#define NHEAD   63                // ceil(1000 / 16) head blocks

// Exact collapse of the reference:
//   g[b,c]     = mean_{h,w} x[b,c,h,w]        (every tree level's hw-mean == g)
//   wfold[c,j] = sum_l emb_w[(l*3+c)*896 + 768+j]
//   ebias[j]   = emb_b[768+j]
//   out[b,k]   = d[k] + sum_c g[b,c]*M[c,k]
//     M[c,k]   = sum_j wfold[c,j]*cls_w[j*1000+k]   (batch-independent!)
//     d[k]     = cls_b[k] + sum_j ebias[j]*cls_w[j*1000+k]
//
// V7: single fused kernel with FULL PREFETCH. All global reads (x slice,
// cls_w columns, emb_w fold rows) are issued in the first ~100 cycles of
// each block, x first so Phase A's vmcnt wait doesn't cover the later
// loads. Collapses the V6 critical path (x-read round -> fold round ->
// cls_w round, each a cold HBM latency under the harness fill's dirty
// writeback drain) into ~one latency round. Epoch-counter sync unchanged
// (snapshot-before-own-increment => floor-to-96 is deadlock-free).

__device__ unsigned g_done = 0;        // monotonic across launches
__device__ float    g_mean[NRED];      // written-before-read every launch

__global__ __launch_bounds__(256) void k_fused(
        const float* __restrict__ x,
        const float* __restrict__ emb_w,
        const float* __restrict__ emb_b,
        const float* __restrict__ cls_w,
        const float* __restrict__ cls_b,
        float* __restrict__ out) {
    const int t  = threadIdx.x;
    const int bc = blockIdx.x;                    // 0..95
    const bool isHead = (bc < NHEAD);
    const int tx = t & 15;
    const int ty = t >> 4;
    const int k  = bc * 16 + tx;
    const bool kok = isHead && (k < NCLS);

    __shared__ float ls[4];
    __shared__ float wf[3 * INNER];    // folded emb weights, [c*128 + j]
    __shared__ float ebs[INNER];
    __shared__ float gsh[NRED];
    __shared__ float4 red[16][16];     // [ty][tx] partial (m0,m1,m2,d)
    __shared__ float4 fin[16];         // [tx] reduced

    // Epoch target: snapshot BEFORE our own increment => snap <= L*96+95,
    // floor-to-96 recovers launch index L exactly.
    unsigned target = 0;
    if (t == 0) {
        unsigned snap = __hip_atomic_load(&g_done, __ATOMIC_RELAXED,
                                          __HIP_MEMORY_SCOPE_AGENT);
        target = (snap / NRED) * NRED + NRED;
    }

    // ---- Issue ALL global loads up front. x first (oldest in vmcnt
    // queue -> Phase A consumes them without waiting for later loads).
    float4 xv[4];
    {
        const float4* p4 = (const float4*)(x + (size_t)bc * HW);
#pragma unroll
        for (int i = 0; i < 4; ++i)
            xv[i] = p4[t + 256 * i];
    }

    float w[8];                         // cls_w column prefetch (head only)
    if (kok) {
        const int jb = ty * 8;
#pragma unroll
        for (int jj = 0; jj < 8; ++jj)
            w[jj] = cls_w[(size_t)(jb + jj) * NCLS + k];
    }

    // emb fold prefetch: 384 column-sums spread over 192 threads, 2 each.
    // Loads land in regs now; summed + written to LDS after Phase A.
    float f0[NLEV], f1[NLEV], ebr = 0.f;
    const int p0 = t, p1 = t + 192;
    const bool fold = isHead && (t < 192);
    if (fold) {
        const int c0 = p0 >> 7, j0 = p0 & 127;
        const int c1 = p1 >> 7, j1 = p1 & 127;
#pragma unroll
        for (int l = 0; l < NLEV; ++l) {
            f0[l] = emb_w[(size_t)(l * CHANS + c0) * NEMBD + ROOTOFF + j0];
            f1[l] = emb_w[(size_t)(l * CHANS + c1) * NEMBD + ROOTOFF + j1];
        }
    }
    if (isHead && t < INNER)
        ebr = emb_b[ROOTOFF + t];

    // ---- Phase A: mean of own x slice, publish ASAP ----
    {
        float s = 0.f;
#pragma unroll
        for (int i = 0; i < 4; ++i)
            s += (xv[i].x + xv[i].y) + (xv[i].z + xv[i].w);
#pragma unroll
        for (int off = 32; off > 0; off >>= 1)
            s += __shfl_down(s, off, 64);
        if ((t & 63) == 0) ls[t >> 6] = s;
        __syncthreads();
        if (t == 0) {
            float mean = (ls[0] + ls[1] + ls[2] + ls[3]) * (1.0f / HW);
            __hip_atomic_store(&g_mean[bc], mean, __ATOMIC_RELAXED,
                               __HIP_MEMORY_SCOPE_AGENT);
            __hip_atomic_fetch_add(&g_done, 1u, __ATOMIC_RELEASE,
                                   __HIP_MEMORY_SCOPE_AGENT);
        }
    }

    if (!isHead) return;   // blocks 63..95 are reduce-only

    // ---- Phase B: fold -> LDS, M/d partials, reduce, wait, fan out ----
    if (fold) {
        float a0 = 0.f, a1 = 0.f;
#pragma unroll
        for (int l = 0; l < NLEV; ++l) { a0 += f0[l]; a1 += f1[l]; }
        wf[p0] = a0;
        wf[p1] = a1;
    }
    if (t < INNER)
        ebs[t] = ebr;
    __syncthreads();

    float m0 = 0.f, m1 = 0.f, m2 = 0.f, dd = 0.f;
    if (kok) {
        const int jb = ty * 8;
#pragma unroll
        for (int jj = 0; jj < 8; ++jj) {
            const int j = jb + jj;
            m0 += wf[0 * INNER + j] * w[jj];
            m1 += wf[1 * INNER + j] * w[jj];
            m2 += wf[2 * INNER + j] * w[jj];
            dd += ebs[j] * w[jj];
        }
    }
    red[ty][tx] = make_float4(m0, m1, m2, dd);
    __syncthreads();

    if (ty == 0) {
        float4 a = make_float4(0.f, 0.f, 0.f, kok ? cls_b[k] : 0.f);
#pragma unroll
        for (int yy = 0; yy < 16; ++yy) {
            float4 p = red[yy][tx];
            a.x += p.x; a.y += p.y; a.z += p.z; a.w += p.w;
        }
        fin[tx] = a;
    }

    // ---- Wait for all 96 means (thread 0 only), then fan out ----
    if (t == 0) {
        while ((int)(__hip_atomic_load(&g_done, __ATOMIC_ACQUIRE,
                                       __HIP_MEMORY_SCOPE_AGENT) - target) < 0)
            __builtin_amdgcn_s_sleep(1);
    }
    __syncthreads();   // orders spin + fin[] writes before readers

    if (t < NRED)
        gsh[t] = __hip_atomic_load(&g_mean[t], __ATOMIC_RELAXED,
                                   __HIP_MEMORY_SCOPE_AGENT);
    __syncthreads();

    if (kok) {
        const float4 m = fin[tx];
#pragma unroll
        for (int h = 0; h < 2; ++h) {
            const int b = ty + 16 * h;
            const float* gb = gsh + b * CHANS;
            out[(size_t)b * NCLS + k] = m.w + gb[0] * m.x + gb[1] * m.y + gb[2] * m.z;
        }
    }
}

extern "C" void kernel_launch(void* const* d_in, const int* in_sizes, int n_in,
                              void* d_out, int out_size, void* d_ws, size_t ws_size,
                              hipStream_t stream) {
    const float* x     = (const float*)d_in[0];
    const float* emb_w = (const float*)d_in[1];
    const float* emb_b = (const float*)d_in[2];
    const float* cls_w = (const float*)d_in[3];
    const float* cls_b = (const float*)d_in[4];
    float* out = (float*)d_out;
    (void)d_ws; (void)ws_size;   // workspace unused (g lives in __device__ mem)

    k_fused<<<NRED, 256, 0, stream>>>(x, emb_w, emb_b, cls_w, cls_b, out);
}